// Round 16
// baseline (168.935 us; speedup 1.0000x reference)
//
#include <hip/hip_runtime.h>
#include <hip/hip_bf16.h>

typedef __attribute__((ext_vector_type(8))) short short8;
typedef __attribute__((ext_vector_type(4))) float f32x4;

#define NTOK   100000
#define H      150
#define NKS    20          // K-steps of 32 (4 segs x 5; s5=4 is overlap-window 118..149)
#define BM     64          // token rows per block
#define OUTOFF (NTOK * H)
#define XLIM   ((long)NTOK * 600 - 16)   // last valid 16B load offset in an X array

__device__ __forceinline__ unsigned short f2bf(float f) {
    unsigned int u = __builtin_bit_cast(unsigned int, f);
    u = (u + 0x7FFFu + ((u >> 16) & 1u)) >> 16;   // RNE
    return (unsigned short)u;
}

// ---------------------------------------------------------------------------
// Prepass: pack weights FRAGMENT-MAJOR (B-frag load = 64 lanes x 16B = 1KB
// contiguous). K-window per step: s5<4 -> k2 = s5*32 + p; s5==4 -> k2 =
// 118 + p with p<10 ZEROED (overlap with s5=3 window; keeps all A-side
// staging fully in-row, no OOB, no read-side masking).
// wb[(((n*NKS + ks)*64 + lane)*8 + j] = Wval
// ---------------------------------------------------------------------------
__global__ void prep_w(const float* __restrict__ w_in, const float* __restrict__ w_out,
                       const float* __restrict__ u_in, const float* __restrict__ u_out,
                       unsigned short* __restrict__ wb) {
    int idx = blockIdx.x * 256 + threadIdx.x;
    if (idx >= 10 * NKS * 64 * 8) return;        // 102400 elems
    int j    = idx & 7;
    int lane = (idx >> 3) & 63;
    int ks   = (idx >> 9) % NKS;
    int n    = idx / (512 * NKS);
    int seg  = ks / 5, s5 = ks % 5;
    int col  = n * 16 + (lane & 15);
    int p    = (lane >> 4) * 8 + j;              // 0..31 within window
    int k2   = (s5 < 4) ? (s5 * 32 + p) : (118 + p);
    bool zero_overlap = (s5 == 4) && (p < 10);   // k2 118..127 already done in s5=3
    float v = 0.0f;
    if (col < H && k2 < H && !zero_overlap) {
        const float* W = (seg == 0) ? w_in : (seg == 1) ? w_out : (seg == 2) ? u_in : u_out;
        v = W[k2 * H + col];
    }
    wb[idx] = f2bf(v);
}

template<int N> __device__ __forceinline__ void vwait() {
    if constexpr (N == 13)     asm volatile("s_waitcnt vmcnt(13)" ::: "memory");
    else if constexpr (N == 9) asm volatile("s_waitcnt vmcnt(9)" ::: "memory");
    else                       asm volatile("s_waitcnt vmcnt(0)" ::: "memory");
}

// ---------------------------------------------------------------------------
// Main fused kernel: wave-private, BARRIER-FREE, depth-2 DMA pipeline.
// Block = 64 rows x 160 cols; 4 waves 2Mx2N, each wave 32 rows x 80 cols.
// Per wave: private triple-buffered 4KB LDS slab (32 rows x 32 k fp32,
// source-swizzled by row&6 for conflict-light reads). Fully unrolled 20
// K-steps: {B(ks+1)->regs, DMA-stage(ks+2), s_waitcnt vmcnt(13), compute}.
// vmcnt is counted (never 0 mid-loop): each HBM stage gets 2 iters of cover.
// ---------------------------------------------------------------------------
__global__ __launch_bounds__(256, 3) void lstm_fused(
        const float* __restrict__ s_in, const float* __restrict__ s_out,
        const float* __restrict__ h_in, const float* __restrict__ h_out,
        const float* __restrict__ last_c, const unsigned short* __restrict__ wb,
        float* __restrict__ out) {
    __shared__ __align__(16) unsigned char Xr[4][3][4096];   // 49152 B -> 3 blocks/CU

    const int t     = threadIdx.x;
    const int lane  = t & 63;
    const int wid   = t >> 6;      // 0..3
    const int waveM = wid >> 1;    // rows waveM*32 + [0,32)
    const int waveN = wid & 1;     // cols waveN*80 + [0,80)
    const int lrow  = lane & 15;
    const int lko   = lane >> 4;
    const int r0blk = blockIdx.x * BM;
    const int rW    = r0blk + waveM * 32;   // wave's first token row

    const float* Xseg[4] = {s_in, s_out, h_in, h_out};

    // per-lane stage source offsets: chunk c covers tile-rows c*8..c*8+7,
    // lane l -> row c*8+(l>>3), slot (l&7) XOR (row&6)  [swizzle involution]
    const int trl = lane >> 3;
    const int swz = (lane & 7) ^ (trl & 6);
    long rowoff[4];
#pragma unroll
    for (int c = 0; c < 4; c++)
        rowoff[c] = (long)(rW + c * 8 + trl) * 600 + swz * 16;

    f32x4 acc[2][5];
#pragma unroll
    for (int m = 0; m < 2; m++)
#pragma unroll
        for (int n = 0; n < 5; n++) acc[m][n] = (f32x4){0.f, 0.f, 0.f, 0.f};

    short8 bfA[5], bfB[5];

    auto STAGE = [&](int ks) {                      // 4 DMA chunks, buf = ks%3
        const char* xb = (const char*)Xseg[ks / 5];
        const int s5 = ks % 5;
        const int sofs = (s5 < 4) ? s5 * 128 : 472; // byte offset in row
        const int buf = ks % 3;
#pragma unroll
        for (int c = 0; c < 4; c++) {
            long go = rowoff[c] + sofs;
            if (go > XLIM) go = XLIM;               // tail-block rows >= NTOK only
            __builtin_amdgcn_global_load_lds(
                (const __attribute__((address_space(1))) void*)(xb + go),
                (__attribute__((address_space(3))) void*)&Xr[wid][buf][c * 1024],
                16, 0, 0);
        }
    };
    auto BLOAD = [&](int ks, short8* dst) {         // 5 x 1KB-contiguous L2 loads
#pragma unroll
        for (int n = 0; n < 5; n++)
            dst[n] = *(const short8*)
                &wb[((((long)waveN * 5 + n) * NKS + ks) * 64 + lane) * 8];
    };
    auto COMPUTE = [&](int ks, const short8* bf) {
        const int buf = ks % 3;
#pragma unroll
        for (int m = 0; m < 2; m++) {
            const int tr = m * 16 + lrow;
            const int p  = (lko * 2) ^ (tr & 6);    // swizzled 32B slot pair
            const f32x4* lp = (const f32x4*)&Xr[wid][buf][tr * 128 + p * 16];
            f32x4 v0 = lp[0], v1 = lp[1];
            short8 af;
            af[0] = (short)f2bf(v0[0]); af[1] = (short)f2bf(v0[1]);
            af[2] = (short)f2bf(v0[2]); af[3] = (short)f2bf(v0[3]);
            af[4] = (short)f2bf(v1[0]); af[5] = (short)f2bf(v1[1]);
            af[6] = (short)f2bf(v1[2]); af[7] = (short)f2bf(v1[3]);
#pragma unroll
            for (int n = 0; n < 5; n++)
                acc[m][n] = __builtin_amdgcn_mfma_f32_16x16x32_bf16(af, bf[n], acc[m][n], 0, 0, 0);
        }
    };

#define ITER(ks, CUR, NXT)                                       \
    {                                                            \
        if ((ks) + 1 < NKS) BLOAD((ks) + 1, NXT);                \
        if ((ks) + 2 < NKS) STAGE((ks) + 2);                     \
        if ((ks) < NKS - 2)       vwait<13>();                   \
        else if ((ks) == NKS - 2) vwait<9>();                    \
        else                      vwait<0>();                    \
        __builtin_amdgcn_sched_barrier(0);                       \
        COMPUTE((ks), CUR);                                      \
    }

    // prologue: fill pipeline (depth 2)
    STAGE(0);
    BLOAD(0, bfA);
    STAGE(1);
    __builtin_amdgcn_sched_barrier(0);

    ITER(0,  bfA, bfB)  ITER(1,  bfB, bfA)  ITER(2,  bfA, bfB)  ITER(3,  bfB, bfA)
    ITER(4,  bfA, bfB)  ITER(5,  bfB, bfA)  ITER(6,  bfA, bfB)  ITER(7,  bfB, bfA)
    ITER(8,  bfA, bfB)  ITER(9,  bfB, bfA)  ITER(10, bfA, bfB)  ITER(11, bfB, bfA)
    ITER(12, bfA, bfB)  ITER(13, bfB, bfA)  ITER(14, bfA, bfB)  ITER(15, bfB, bfA)
    ITER(16, bfA, bfB)  ITER(17, bfB, bfA)  ITER(18, bfA, bfB)  ITER(19, bfB, bfA)
#undef ITER

    // ---- fused epilogue: g=sigmoid(pre); cell=g*lc+g*g; hid=g*tanh(cell)
#pragma unroll
    for (int m = 0; m < 2; m++) {
#pragma unroll
        for (int r = 0; r < 4; r++) {
            const int row = r0blk + waveM * 32 + m * 16 + lko * 4 + r;
            if (row >= NTOK) continue;
            const long rb = (long)row * H;
#pragma unroll
            for (int n = 0; n < 5; n++) {
                const int col = waveN * 80 + n * 16 + lrow;
                if (col >= H) continue;
                float pre = acc[m][n][r];
                float e   = __expf(-pre);
                float g   = __builtin_amdgcn_rcpf(1.f + e);
                float lc  = last_c[rb + col];
                float cell = g * lc + g * g;
                float e2  = __expf(-2.f * cell);
                float th  = (1.f - e2) * __builtin_amdgcn_rcpf(1.f + e2);
                out[rb + col]          = g * th;
                out[OUTOFF + rb + col] = cell;
            }
        }
    }
}

extern "C" void kernel_launch(void* const* d_in, const int* in_sizes, int n_in,
                              void* d_out, int out_size, void* d_ws, size_t ws_size,
                              hipStream_t stream) {
    const float* s_in   = (const float*)d_in[0];
    const float* s_out  = (const float*)d_in[1];
    const float* h_in   = (const float*)d_in[2];
    const float* h_out  = (const float*)d_in[3];
    const float* last_c = (const float*)d_in[4];
    const float* w_in   = (const float*)d_in[5];
    const float* w_out  = (const float*)d_in[6];
    const float* u_in   = (const float*)d_in[7];
    const float* u_out  = (const float*)d_in[8];

    unsigned short* wb = (unsigned short*)d_ws;   // 102400*2 = 204800 B
    float* out = (float*)d_out;

    prep_w<<<(10 * NKS * 64 * 8 + 255) / 256, 256, 0, stream>>>(w_in, w_out, u_in, u_out, wb);

    const int nblocks = (NTOK + BM - 1) / BM;  // 1563 blocks, 4 waves (2Mx2N)
    lstm_fused<<<nblocks, 256, 0, stream>>>(s_in, s_out, h_in, h_out, last_c, wb, out);
}